// Round 11
// baseline (388.300 us; speedup 1.0000x reference)
//
#include <hip/hip_runtime.h>
#include <stdint.h>

// ---------------------------------------------------------------------------
// MLP_Model: candidates head + per-route Customer MLP + 2-layer GRU + FC head
// R14 = R13 + Phase A depth-2 software pipeline: the 3 tt-steps are manually
// unrolled with ping-pong load buffers (uA/uB); step k+1's six customer
// float4 loads are issued BEFORE step k's compute, hiding ~900cyc HBM
// latency under the current step's 48 MFMAs + tanh epilogue. No runtime-
// indexed buffers (rule #20), no register copies. Phase B unchanged.
// LDS layout unchanged from R13 (Phase A bias table in dedicated region).
// ws layout: [0,344064) packed bf16 weights; hout fp32 at HOUT_BYTE.
// ---------------------------------------------------------------------------

#define NSEQ   24576   // 512 * 48
#define TSTEPS 24
#define SEQB   32      // sequences per gru block (2 tiles of 16)

typedef __attribute__((ext_vector_type(8))) short bf16x8;
typedef __attribute__((ext_vector_type(4))) float floatx4;

// packed-weight element offsets (uint16 units)
#define PK_W1    0
#define PK_W2    8192
#define PK_WIH0  12288
#define PK_WHH0  24576
#define PK_WIH1  73728
#define PK_WHH1  122880
#define PK_END   172032
#define HOUT_BYTE 38092800              // h1 final: [seq][128] fp32

// fused-kernel LDS layout (uint16 element offsets)
#define SCR_EL   4352                   // per-wave scratch: 32*136 (J=0..7 -> [0,34816))
#define H1L_EL   8704                   // h1 double buffer base (phase B; aliases scr[2..3])
#define BIAS_EL  17408                  // phase B bias table (written AFTER phase A)
#define X2L_EL   34816                  // x2l: [24][32][32] bf16
#define BIASA_EL 59392                  // phase A bias table: float[160] (320 el)
#define LDS_EL   59712                  // total elements (119424 B)

#define MFMA(a,b,c) c = __builtin_amdgcn_mfma_f32_16x16x32_bf16(a, b, c, 0, 0, 0)

__device__ __forceinline__ uint16_t f2bf(float f) {
  uint32_t u = __float_as_uint(f);
  u += 0x7FFFu + ((u >> 16) & 1u);           // RNE
  return (uint16_t)(u >> 16);
}
// packed f32x2 -> bf16x2 (RNE), single VALU op. lo half = first arg.
__device__ __forceinline__ uint32_t cvt_pk(float a, float b) {
  uint32_t r;
  asm("v_cvt_pk_bf16_f32 %0, %1, %2" : "=v"(r) : "v"(a), "v"(b));
  return r;
}
__device__ __forceinline__ float fast_sigmoid(float x) {
  float e = __builtin_amdgcn_exp2f(-1.4426950408889634f * x);
  return __builtin_amdgcn_rcpf(1.0f + e);
}
__device__ __forceinline__ float fast_tanh(float x) {
  float e = __builtin_amdgcn_exp2f(-2.8853900817779268f * x);
  return 2.0f * __builtin_amdgcn_rcpf(1.0f + e) - 1.0f;
}
__device__ __forceinline__ bf16x8 ldf(const uint16_t* p) {
  return *(const bf16x8*)p;
}

// ---------------------------------------------------------------------------
// Kernel 0: pack all weights to bf16 fragment layout. (unchanged)
// ---------------------------------------------------------------------------
__global__ __launch_bounds__(256) void pack_weights(
    const float* __restrict__ w1, const float* __restrict__ w2,
    const float* __restrict__ wih0, const float* __restrict__ whh0,
    const float* __restrict__ wih1, const float* __restrict__ whh1,
    uint16_t* __restrict__ ws) {
  int idx = blockIdx.x * 256 + threadIdx.x;
  if (idx >= PK_END) return;
  const float* W; int N, KB, Kreal, base;
  if      (idx <  8192) { W = w1;   N = 128; KB = 2; Kreal = 36;  base = 0; }
  else if (idx < 12288) { W = w2;   N = 32;  KB = 4; Kreal = 128; base = 8192; }
  else if (idx < 24576) { W = wih0; N = 384; KB = 1; Kreal = 32;  base = 12288; }
  else if (idx < 73728) { W = whh0; N = 384; KB = 4; Kreal = 128; base = 24576; }
  else if (idx < 122880){ W = wih1; N = 384; KB = 4; Kreal = 128; base = 73728; }
  else                  { W = whh1; N = 384; KB = 4; Kreal = 128; base = 122880; }
  int li = idx - base;
  int frag = li >> 9;
  int e = li & 511;
  int lane = e >> 3, j = e & 7;
  int kb = frag % KB, nt = frag / KB;
  int k = kb * 32 + (lane >> 4) * 8 + j;
  int n = nt * 16 + (lane & 15);
  float v = (k < Kreal) ? W[k * N + n] : 0.0f;
  ws[base + li] = f2bf(v);
}

// ---------------------------------------------------------------------------
// Kernel 1 (R14): FUSED customer-MLP + 2-layer GRU. Grid 768 x 512 threads.
// ---------------------------------------------------------------------------
__global__ __launch_bounds__(512, 2) void gru_fused(
    const float* __restrict__ customers, const float* __restrict__ b1,
    const float* __restrict__ b2, const uint16_t* __restrict__ wpk,
    const float* __restrict__ bih0, const float* __restrict__ bhh0,
    const float* __restrict__ bih1, const float* __restrict__ bhh1,
    float* __restrict__ hout) {
  __shared__ __align__(16) uint16_t lds[LDS_EL];
  const int seq0 = blockIdx.x * SEQB;
  const int tid = threadIdx.x;
  const int J = tid >> 6, l = tid & 63, q = l >> 4, c = l & 15;
  const int lo8 = l * 8;
  const int hbA = 4 * q;             // phase A: lane's 4 rows within a tile
  const int hb  = J * 16 + 4 * q;    // phase B: lane's 4 hidden cols

  // ---- stage b1/b2 into dedicated LDS region (no aliasing with scratch) ----
  float* biasA = (float*)(lds + BIASA_EL);
  if (tid < 160) biasA[tid] = (tid < 128) ? b1[tid] : b2[tid - 128];
  __syncthreads();

  // ================ Phase A: customer MLP, depth-2 pipelined ================
  {
    uint16_t* scr = lds + J * SCR_EL;       // private [32][136]
    uint16_t* x2l = lds + X2L_EL;           // [24][32][32]

    // hoisted weight fragments: W1 (16) + W2 (8) = 96 VGPR, dead after A
    bf16x8 w1f[16], w2f[8];
    #pragma unroll
    for (int i = 0; i < 16; ++i) w1f[i] = ldf(wpk + PK_W1 + i * 512 + lo8);
    #pragma unroll
    for (int i = 0; i < 8; ++i)  w2f[i] = ldf(wpk + PK_W2 + i * 512 + lo8);

    floatx4 uA0[2], uA1[2], uA2[2], uB0[2], uB1[2], uB2[2];

    // issue customer loads for timestep T into (U0,U1,U2)
    #define A_LOAD(T, U0, U1, U2)                                           \
    {                                                                       \
      _Pragma("unroll")                                                     \
      for (int mi = 0; mi < 2; ++mi) {                                      \
        const float* xp = customers + (size_t)(seq0 + mi * 16 + c) * 864 + (T) * 36; \
        U0[mi] = *(const floatx4*)(xp + q * 8);                             \
        U1[mi] = *(const floatx4*)(xp + q * 8 + 4);                        \
        U2[mi] = *(const floatx4*)(xp + 32);   /* in-bounds; used if q==0 */\
      }                                                                     \
    }

    // full MLP step for timestep T consuming (U0,U1,U2)
    #define A_STEP(T, U0, U1, U2)                                           \
    {                                                                       \
      floatx4 acc[2][8];                                                    \
      _Pragma("unroll")                                                     \
      for (int mi = 0; mi < 2; ++mi)                                        \
        _Pragma("unroll")                                                   \
        for (int nt = 0; nt < 8; ++nt) acc[mi][nt] = (floatx4){0.f,0.f,0.f,0.f}; \
      _Pragma("unroll")                                                     \
      for (int mi = 0; mi < 2; ++mi) {                                      \
        bf16x8 a0;                                                          \
        { uint32_t* a0u = (uint32_t*)&a0;                                   \
          a0u[0] = cvt_pk(U0[mi][0], U0[mi][1]); a0u[1] = cvt_pk(U0[mi][2], U0[mi][3]); \
          a0u[2] = cvt_pk(U1[mi][0], U1[mi][1]); a0u[3] = cvt_pk(U1[mi][2], U1[mi][3]); } \
        bf16x8 a1x = (bf16x8){0,0,0,0,0,0,0,0};                             \
        if (q == 0) {                                                       \
          uint32_t* a1u = (uint32_t*)&a1x;                                  \
          a1u[0] = cvt_pk(U2[mi][0], U2[mi][1]); a1u[1] = cvt_pk(U2[mi][2], U2[mi][3]); \
        }                                                                   \
        _Pragma("unroll")                                                   \
        for (int nt = 0; nt < 8; ++nt) {                                    \
          MFMA(w1f[nt * 2 + 0], a0,  acc[mi][nt]);                          \
          MFMA(w1f[nt * 2 + 1], a1x, acc[mi][nt]);                          \
        }                                                                   \
      }                                                                     \
      _Pragma("unroll")                                                     \
      for (int mi = 0; mi < 2; ++mi)                                        \
        _Pragma("unroll")                                                   \
        for (int nt = 0; nt < 8; ++nt) {                                    \
          const floatx4 bv = *(const floatx4*)&biasA[nt * 16 + hbA];        \
          float o0 = fast_tanh(acc[mi][nt][0] + bv[0]);                     \
          float o1 = fast_tanh(acc[mi][nt][1] + bv[1]);                     \
          float o2 = fast_tanh(acc[mi][nt][2] + bv[2]);                     \
          float o3 = fast_tanh(acc[mi][nt][3] + bv[3]);                     \
          uint2 pk; pk.x = cvt_pk(o0, o1); pk.y = cvt_pk(o2, o3);           \
          *(uint2*)&scr[(mi * 16 + c) * 136 + nt * 16 + hbA] = pk;          \
        }                                                                   \
      floatx4 acc2[2][2];                                                   \
      _Pragma("unroll")                                                     \
      for (int mi = 0; mi < 2; ++mi)                                        \
        _Pragma("unroll")                                                   \
        for (int nt = 0; nt < 2; ++nt) acc2[mi][nt] = (floatx4){0.f,0.f,0.f,0.f}; \
      _Pragma("unroll")                                                     \
      for (int kb = 0; kb < 4; ++kb) {                                      \
        bf16x8 av0 = ldf(&scr[(c)      * 136 + kb * 32 + q * 8]);           \
        bf16x8 av1 = ldf(&scr[(16 + c) * 136 + kb * 32 + q * 8]);           \
        _Pragma("unroll")                                                   \
        for (int nt = 0; nt < 2; ++nt) {                                    \
          MFMA(w2f[nt * 4 + kb], av0, acc2[0][nt]);                         \
          MFMA(w2f[nt * 4 + kb], av1, acc2[1][nt]);                         \
        }                                                                   \
      }                                                                     \
      _Pragma("unroll")                                                     \
      for (int mi = 0; mi < 2; ++mi)                                        \
        _Pragma("unroll")                                                   \
        for (int nt = 0; nt < 2; ++nt) {                                    \
          const floatx4 bv = *(const floatx4*)&biasA[128 + nt * 16 + hbA];  \
          float o0 = fast_tanh(acc2[mi][nt][0] + bv[0]);                    \
          float o1 = fast_tanh(acc2[mi][nt][1] + bv[1]);                    \
          float o2 = fast_tanh(acc2[mi][nt][2] + bv[2]);                    \
          float o3 = fast_tanh(acc2[mi][nt][3] + bv[3]);                    \
          uint2 pk; pk.x = cvt_pk(o0, o1); pk.y = cvt_pk(o2, o3);           \
          *(uint2*)&x2l[(T) * 1024 + (mi * 16 + c) * 32 + nt * 16 + hbA] = pk; \
        }                                                                   \
    }

    // 3-stage manual pipeline: loads for step k+1 in flight during step k
    A_LOAD(J,      uA0, uA1, uA2)     // step 0 loads
    A_LOAD(8 + J,  uB0, uB1, uB2)     // step 1 loads (in flight during step 0)
    A_STEP(J,      uA0, uA1, uA2)
    A_LOAD(16 + J, uA0, uA1, uA2)     // step 2 loads (in flight during step 1)
    A_STEP(8 + J,  uB0, uB1, uB2)
    A_STEP(16 + J, uA0, uA1, uA2)
    #undef A_LOAD
    #undef A_STEP
  }
  __syncthreads();
  __builtin_amdgcn_sched_barrier(0);   // keep phase-B weight loads below

  // ================ Phase B: fused 2-layer GRU (R10 structure) ================
  const uint16_t* x2l = lds + X2L_EL;
  // zero h1[-1] (h1 buffer 0)
  for (int i = tid; i < 2176; i += 512) ((uint32_t*)(lds + H1L_EL))[i] = 0u;
  // bias table (float[8][128] at BIAS_EL; safe now — Phase A is done)
  float* biasf = (float*)(lds + BIAS_EL);
  for (int i = tid; i < 1024; i += 512) {
    int g = i >> 7, k = i & 127;
    float v;
    if      (g == 0) v = bih0[k]       + bhh0[k];
    else if (g == 1) v = bih0[128 + k] + bhh0[128 + k];
    else if (g == 2) v = bih0[256 + k];
    else if (g == 3) v = bhh0[256 + k];
    else if (g == 4) v = bih1[k]       + bhh1[k];
    else if (g == 5) v = bih1[128 + k] + bhh1[128 + k];
    else if (g == 6) v = bih1[256 + k];
    else             v = bhh1[256 + k];
    biasf[g * 128 + k] = v;
  }

  // ---- this wave's weight fragments (A-operands) into VGPRs (39 frags) ----
  bf16x8 wi0[3], wh0[3][4], wi1[3][4], wh1[3][4];
  #pragma unroll
  for (int g = 0; g < 3; ++g) {
    wi0[g] = ldf(wpk + PK_WIH0 + (g * 8 + J) * 512 + lo8);
    #pragma unroll
    for (int kb = 0; kb < 4; ++kb) {
      wh0[g][kb] = ldf(wpk + PK_WHH0 + ((g * 8 + J) * 4 + kb) * 512 + lo8);
      wi1[g][kb] = ldf(wpk + PK_WIH1 + ((g * 8 + J) * 4 + kb) * 512 + lo8);
      wh1[g][kb] = ldf(wpk + PK_WHH1 + ((g * 8 + J) * 4 + kb) * 512 + lo8);
    }
  }

  floatx4 h0m0 = (floatx4){0.f,0.f,0.f,0.f}, h0m1 = (floatx4){0.f,0.f,0.f,0.f};
  floatx4 h1m0 = (floatx4){0.f,0.f,0.f,0.f}, h1m1 = (floatx4){0.f,0.f,0.f,0.f};

  __syncthreads();   // biasf + zeroed h1 buffer visible

  // ---- prologue: L0[0] with h0[-1]=0 (skip Whh MFMAs) -> h0 buffer 0 ----
  {
    bf16x8 ax_0 = ldf(x2l + (c)      * 32 + q * 8);          // x[0]
    bf16x8 ax_1 = ldf(x2l + (16 + c) * 32 + q * 8);
    #define GRU_PRO(TI, AX, H0M)                                            \
    {                                                                       \
      floatx4 aR = *(const floatx4*)&biasf[0 * 128 + hb];                   \
      floatx4 aZ = *(const floatx4*)&biasf[1 * 128 + hb];                   \
      floatx4 aN = *(const floatx4*)&biasf[2 * 128 + hb];                   \
      floatx4 aH = *(const floatx4*)&biasf[3 * 128 + hb];                   \
      MFMA(wi0[0], AX, aR); MFMA(wi0[1], AX, aZ); MFMA(wi0[2], AX, aN);     \
      float o[4];                                                           \
      _Pragma("unroll")                                                     \
      for (int e = 0; e < 4; ++e) {                                         \
        float r  = fast_sigmoid(aR[e]);                                     \
        float zz = fast_sigmoid(aZ[e]);                                     \
        float nn = fast_tanh(aN[e] + r * aH[e]);                            \
        o[e] = nn - zz * nn;                                                \
        H0M[e] = o[e];                                                      \
      }                                                                     \
      uint2 pk; pk.x = cvt_pk(o[0], o[1]); pk.y = cvt_pk(o[2], o[3]);       \
      *(uint2*)(lds + ((TI) * 16 + c) * 136 + hb) = pk;                     \
    }
    GRU_PRO(0, ax_0, h0m0)
    GRU_PRO(1, ax_1, h0m1)
    #undef GRU_PRO
  }
  __syncthreads();

  // per-tile phase body: {L1[t], L0[t+1]} for 16 seqs, accs reused across tiles
  #define GRU_TILE(TI, AX, H0M, H1M)                                        \
  {                                                                         \
    floatx4 aR1 = *(const floatx4*)&biasf[4 * 128 + hb];                    \
    floatx4 aZ1 = *(const floatx4*)&biasf[5 * 128 + hb];                    \
    floatx4 aN1 = *(const floatx4*)&biasf[6 * 128 + hb];                    \
    floatx4 aH1 = *(const floatx4*)&biasf[7 * 128 + hb];                    \
    floatx4 aR0 = *(const floatx4*)&biasf[0 * 128 + hb];                    \
    floatx4 aZ0 = *(const floatx4*)&biasf[1 * 128 + hb];                    \
    floatx4 aN0 = *(const floatx4*)&biasf[2 * 128 + hb];                    \
    floatx4 aH0 = *(const floatx4*)&biasf[3 * 128 + hb];                    \
    _Pragma("unroll")                                                       \
    for (int kb = 0; kb < 4; ++kb) {                                        \
      bf16x8 a0 = ldf(h0cur + ((TI) * 16 + c) * 136 + kb * 32 + q * 8);     \
      bf16x8 ah = ldf(h1prv + ((TI) * 16 + c) * 136 + kb * 32 + q * 8);     \
      MFMA(wi1[0][kb], a0, aR1); MFMA(wh1[0][kb], ah, aR1);                 \
      MFMA(wi1[1][kb], a0, aZ1); MFMA(wh1[1][kb], ah, aZ1);                 \
      MFMA(wi1[2][kb], a0, aN1); MFMA(wh1[2][kb], ah, aH1);                 \
      MFMA(wh0[0][kb], a0, aR0);                                            \
      MFMA(wh0[1][kb], a0, aZ0);                                            \
      MFMA(wh0[2][kb], a0, aH0);                                            \
    }                                                                       \
    MFMA(wi0[0], AX, aR0); MFMA(wi0[1], AX, aZ0); MFMA(wi0[2], AX, aN0);    \
    { /* L1 epilogue -> h1[t] */                                            \
      float o[4];                                                           \
      _Pragma("unroll")                                                     \
      for (int e = 0; e < 4; ++e) {                                         \
        float r  = fast_sigmoid(aR1[e]);                                    \
        float zz = fast_sigmoid(aZ1[e]);                                    \
        float nn = fast_tanh(aN1[e] + r * aH1[e]);                          \
        o[e] = nn + zz * (H1M[e] - nn);                                     \
        H1M[e] = o[e];                                                      \
      }                                                                     \
      uint2 pk; pk.x = cvt_pk(o[0], o[1]); pk.y = cvt_pk(o[2], o[3]);       \
      *(uint2*)(h1cur + ((TI) * 16 + c) * 136 + hb) = pk;                   \
    }                                                                       \
    { /* L0 epilogue -> h0[t+1] */                                          \
      float o[4];                                                           \
      _Pragma("unroll")                                                     \
      for (int e = 0; e < 4; ++e) {                                         \
        float r  = fast_sigmoid(aR0[e]);                                    \
        float zz = fast_sigmoid(aZ0[e]);                                    \
        float nn = fast_tanh(aN0[e] + r * aH0[e]);                          \
        o[e] = nn + zz * (H0M[e] - nn);                                     \
        H0M[e] = o[e];                                                      \
      }                                                                     \
      uint2 pk; pk.x = cvt_pk(o[0], o[1]); pk.y = cvt_pk(o[2], o[3]);       \
      *(uint2*)(h0nxt + ((TI) * 16 + c) * 136 + hb) = pk;                   \
    }                                                                       \
  }

  #pragma unroll 1
  for (int t = 0; t < TSTEPS - 1; ++t) {
    uint16_t* h0cur = lds + (t & 1) * SCR_EL;
    uint16_t* h1prv = lds + H1L_EL + (t & 1) * SCR_EL;
    uint16_t* h0nxt = lds + ((t + 1) & 1) * SCR_EL;
    uint16_t* h1cur = lds + H1L_EL + ((t + 1) & 1) * SCR_EL;
    bf16x8 ax_0 = ldf(x2l + (t + 1) * 1024 + (c)      * 32 + q * 8);
    bf16x8 ax_1 = ldf(x2l + (t + 1) * 1024 + (16 + c) * 32 + q * 8);

    GRU_TILE(0, ax_0, h0m0, h1m0)
    __builtin_amdgcn_sched_barrier(0);   // pin tile split: acc regs reused
    GRU_TILE(1, ax_1, h0m1, h1m1)

    __syncthreads();
  }
  #undef GRU_TILE

  // ---- peeled final phase t=23: L1 only, no LDS stores, no barrier ----
  {
    const uint16_t* h0cur = lds + ((TSTEPS - 1) & 1) * SCR_EL;
    const uint16_t* h1prv = lds + H1L_EL + ((TSTEPS - 1) & 1) * SCR_EL;
    #define GRU_LAST(TI, H1M)                                               \
    {                                                                       \
      floatx4 aR1 = *(const floatx4*)&biasf[4 * 128 + hb];                  \
      floatx4 aZ1 = *(const floatx4*)&biasf[5 * 128 + hb];                  \
      floatx4 aN1 = *(const floatx4*)&biasf[6 * 128 + hb];                  \
      floatx4 aH1 = *(const floatx4*)&biasf[7 * 128 + hb];                  \
      _Pragma("unroll")                                                     \
      for (int kb = 0; kb < 4; ++kb) {                                      \
        bf16x8 a0 = ldf(h0cur + ((TI) * 16 + c) * 136 + kb * 32 + q * 8);   \
        bf16x8 ah = ldf(h1prv + ((TI) * 16 + c) * 136 + kb * 32 + q * 8);   \
        MFMA(wi1[0][kb], a0, aR1); MFMA(wh1[0][kb], ah, aR1);               \
        MFMA(wi1[1][kb], a0, aZ1); MFMA(wh1[1][kb], ah, aZ1);               \
        MFMA(wi1[2][kb], a0, aN1); MFMA(wh1[2][kb], ah, aH1);               \
      }                                                                     \
      _Pragma("unroll")                                                     \
      for (int e = 0; e < 4; ++e) {                                         \
        float r  = fast_sigmoid(aR1[e]);                                    \
        float zz = fast_sigmoid(aZ1[e]);                                    \
        float nn = fast_tanh(aN1[e] + r * aH1[e]);                          \
        H1M[e] = nn + zz * (H1M[e] - nn);                                   \
      }                                                                     \
    }
    GRU_LAST(0, h1m0)
    GRU_LAST(1, h1m1)
    #undef GRU_LAST
  }

  *(floatx4*)(hout + (size_t)(seq0 + c) * 128 + hb) = h1m0;
  *(floatx4*)(hout + (size_t)(seq0 + 16 + c) * 128 + hb) = h1m1;
}

// ---------------------------------------------------------------------------
// Kernel 2: mean over routes + candidate head + fc1/fc2/fc3 (unchanged)
// ---------------------------------------------------------------------------
__global__ __launch_bounds__(192) void final_kernel(
    const float* __restrict__ hout, const float* __restrict__ cands,
    const float* __restrict__ cw, const float* __restrict__ cb,
    const float* __restrict__ f1w, const float* __restrict__ f1b,
    const float* __restrict__ f2w, const float* __restrict__ f2b,
    const float* __restrict__ f3w, const float* __restrict__ f3b,
    float* __restrict__ out) {
  __shared__ float hc[192];
  __shared__ float v1[128];
  __shared__ float v2[128];
  __shared__ float red[128];
  const int b = blockIdx.x, tid = threadIdx.x;
  if (tid < 128) {
    float s = 0.f;
    const float* hp = hout + (size_t)(b * 48) * 128 + tid;
    #pragma unroll 4
    for (int r = 0; r < 48; ++r) s += hp[r * 128];
    hc[tid] = s * (1.0f / 48.0f);
  } else {
    int j = tid - 128;
    float s = cb[j];
    const float* cp = cands + b * 72;
    #pragma unroll 8
    for (int k = 0; k < 72; ++k) s += cp[k] * cw[k * 64 + j];
    hc[128 + j] = s;
  }
  __syncthreads();
  if (tid < 128) {
    float s = f1b[tid];
    for (int k = 0; k < 192; ++k) s += hc[k] * f1w[k * 128 + tid];
    v1[tid] = fast_tanh(s);
  }
  __syncthreads();
  if (tid < 128) {
    float s = f2b[tid];
    for (int k = 0; k < 128; ++k) s += v1[k] * f2w[k * 128 + tid];
    v2[tid] = fast_tanh(s);
  }
  __syncthreads();
  if (tid < 128) red[tid] = v2[tid] * f3w[tid];
  __syncthreads();
  if (tid < 64) {
    float s = red[tid] + red[tid + 64];
    s += __shfl_down(s, 32);
    s += __shfl_down(s, 16);
    s += __shfl_down(s, 8);
    s += __shfl_down(s, 4);
    s += __shfl_down(s, 2);
    s += __shfl_down(s, 1);
    if (tid == 0) out[b] = s + f3b[0];
  }
}

// ---------------------------------------------------------------------------
extern "C" void kernel_launch(void* const* d_in, const int* in_sizes, int n_in,
                              void* d_out, int out_size, void* d_ws, size_t ws_size,
                              hipStream_t stream) {
  const float* cand  = (const float*)d_in[0];
  const float* cust  = (const float*)d_in[1];
  const float* w1    = (const float*)d_in[2];
  const float* b1    = (const float*)d_in[3];
  const float* w2    = (const float*)d_in[4];
  const float* b2    = (const float*)d_in[5];
  const float* wih0  = (const float*)d_in[6];
  const float* whh0  = (const float*)d_in[7];
  const float* bih0  = (const float*)d_in[8];
  const float* bhh0  = (const float*)d_in[9];
  const float* wih1  = (const float*)d_in[10];
  const float* whh1  = (const float*)d_in[11];
  const float* bih1  = (const float*)d_in[12];
  const float* bhh1  = (const float*)d_in[13];
  const float* cw    = (const float*)d_in[14];
  const float* cb    = (const float*)d_in[15];
  const float* f1w   = (const float*)d_in[16];
  const float* f1b   = (const float*)d_in[17];
  const float* f2w   = (const float*)d_in[18];
  const float* f2b   = (const float*)d_in[19];
  const float* f3w   = (const float*)d_in[20];
  const float* f3b   = (const float*)d_in[21];

  uint16_t* wsp = (uint16_t*)d_ws;
  float* hout = (float*)((char*)d_ws + HOUT_BYTE);
  float* outp = (float*)d_out;

  pack_weights<<<(PK_END + 255) / 256, 256, 0, stream>>>(w1, w2, wih0, whh0, wih1, whh1, wsp);
  gru_fused<<<NSEQ / SEQB, 512, 0, stream>>>(cust, b1, b2, wsp, bih0, bhh0, bih1, bhh1, hout);
  final_kernel<<<512, 192, 0, stream>>>(hout, cand, cw, cb, f1w, f1b, f2w, f2b, f3w, f3b, outp);
}